// Round 6
// baseline (159.595 us; speedup 1.0000x reference)
//
#include <hip/hip_runtime.h>
#include <hip/hip_bf16.h>

#define N_PTS  4096
#define M_Q    16384
#define C_IN   256
#define C_SKIP 128
#define C_H    384      // C_IN + C_SKIP
#define HDIM   256
#define QB     64       // queries per block -> 256 blocks = 1/CU
#define NW     16       // waves per block (1024 threads)

typedef __bf16 bf16x8 __attribute__((ext_vector_type(8)));
typedef float  f32x4  __attribute__((ext_vector_type(4)));

__device__ __forceinline__ void insert3(float d, int j,
                                        float& b0, float& b1, float& b2,
                                        int& i0, int& i1, int& i2) {
    if (d < b2) {
        if (d < b1) {
            b2 = b1; i2 = i1;
            if (d < b0) { b1 = b0; i1 = i0; b0 = d; i0 = j; }
            else        { b1 = d;  i1 = j; }
        } else { b2 = d; i2 = j; }
    }
}

// ---- Phase 0: fused prep — W1/W2 convert+transpose, pos4 build, out tail ---
__global__ __launch_bounds__(256) void prep_tail_kernel(
        const float* __restrict__ W1, const float* __restrict__ W2,
        const float* __restrict__ pos, const float* __restrict__ pos_skip,
        __hip_bfloat16* __restrict__ W1t, __hip_bfloat16* __restrict__ W2t,
        float4* __restrict__ pos4, float* __restrict__ out, int out_size) {
    const int i = blockIdx.x * 256 + threadIdx.x;
    if (i < C_H * HDIM) {
        const int k = i / HDIM, n = i % HDIM;
        W1t[n * C_H + k] = __float2bfloat16(W1[i]);
    } else if (i < C_H * HDIM + HDIM * HDIM) {
        const int j = i - C_H * HDIM;
        const int k = j / HDIM, n = j % HDIM;
        W2t[n * HDIM + k] = __float2bfloat16(W2[j]);
    } else if (i < C_H * HDIM + HDIM * HDIM + N_PTS) {
        const int j = i - (C_H * HDIM + HDIM * HDIM);
        const float px = pos[j*3+0], py = pos[j*3+1], pz = pos[j*3+2];
        pos4[j] = make_float4(px, py, pz, px*px + py*py + pz*pz);
    }
    // output tail: pos_skip passthrough + zero pad (runs before mega writes)
    if (i < M_Q * 3) out[(size_t)M_Q * HDIM + i] = pos_skip[i];
    const int zbase = M_Q * HDIM + M_Q * 3;
    if (zbase + i < out_size) out[zbase + i] = 0.0f;
}

// ---- Mega kernel v4: 1024 threads = 16 waves -> 4 waves/SIMD --------------
// Same verified phase structure as v3 (kNN -> merge -> gather -> GEMM1 ->
// ReLU -> GEMM2), same LDS overlay map (100.8 KB, 1 block/CU). Doubled wave
// count halves exposed latency: wave w scans 256 points (lane = query);
// GEMM re-tiled 4m x 4n (per-wave 16x64 output). VGPR capped at 128 for
// 4 waves/SIMD via launch_bounds.
__global__ __launch_bounds__(1024, 4) void mega_kernel(
        const float4* __restrict__ pos4, const float* __restrict__ pos_skip,
        const float* __restrict__ x, const float* __restrict__ x_skip,
        const __bf16* __restrict__ W1t, const __bf16* __restrict__ W2t,
        const float* __restrict__ b1, const float* __restrict__ b2,
        float* __restrict__ out) {
    __shared__ __align__(16) char smem[100864];
    float4*         posL  = (float4*)smem;                    // [4096]   64 KB (phase A)
    __hip_bfloat16* h     = (__hip_bfloat16*)smem;            // [64][392] 50.2 KB (phase C, overlays posL)
    __hip_bfloat16* hid   = (__hip_bfloat16*)(smem + 65536);  // [64][264] 33.8 KB (phase D)
    float*          candD = (float*)(smem + 65536);           // [16][64][3] 12 KB (A/B, overlays hid)
    int*            candI = (int*)  (smem + 77824);           // [16][64][3] 12 KB
    int*            idxL  = (int*)  (smem + 99328);           // [192]
    float*          wnL   = (float*)(smem + 100096);          // [192]

    const int t    = threadIdx.x;
    const int m0   = blockIdx.x * QB;
    const int wave = t >> 6, lane = t & 63;

    // ---- stage all points (coalesced, 4 float4/thread) ----
    #pragma unroll
    for (int k = 0; k < N_PTS / 1024; ++k)
        posL[k * 1024 + t] = pos4[k * 1024 + t];

    // ---- preload x_skip to regs: consumed after merge (issue-early) ----
    float4 skipv[2];
    #pragma unroll
    for (int p = 0; p < 2; ++p) {
        const int g = p * 1024 + t;                // 0..2047
        const int r = g >> 5, c = (g & 31) * 4;
        skipv[p] = *(const float4*)(x_skip + (size_t)(m0 + r) * C_SKIP + c);
    }

    const int q = m0 + lane;
    const float qx = pos_skip[q*3+0], qy = pos_skip[q*3+1], qz = pos_skip[q*3+2];
    const float m2x = -2.0f * qx, m2y = -2.0f * qy, m2z = -2.0f * qz;
    __syncthreads();

    // ---- Phase A: kNN scan; wave w owns points [w*256,(w+1)*256) ----
    {
        const int j0 = wave * (N_PTS / NW);
        float bb0 = 3e38f, bb1 = 3e38f, bb2 = 3e38f;
        int   ii0 = 0, ii1 = 0, ii2 = 0;
        #pragma unroll 8
        for (int j = 0; j < N_PTS / NW; ++j) {
            const float4 p = posL[j0 + j];         // uniform addr -> LDS broadcast
            const float d = fmaf(p.x, m2x, fmaf(p.y, m2y, fmaf(p.z, m2z, p.w)));
            const int  jj = j0 + j;
            const bool c0 = d < bb0, c1 = d < bb1, c2 = d < bb2;
            ii2 = c2 ? (c1 ? ii1 : jj) : ii2;
            ii1 = c1 ? (c0 ? ii0 : jj) : ii1;
            ii0 = c0 ? jj : ii0;
            bb2 = __builtin_amdgcn_fmed3f(d, bb1, bb2);  // branch-free top-3 values
            bb1 = __builtin_amdgcn_fmed3f(d, bb0, bb1);
            bb0 = fminf(bb0, d);
        }
        const int ci = (wave * 64 + lane) * 3;
        candD[ci+0] = bb0; candD[ci+1] = bb1; candD[ci+2] = bb2;
        candI[ci+0] = ii0; candI[ci+1] = ii1; candI[ci+2] = ii2;
    }
    __syncthreads();

    // ---- Phase B: merge 48 cands/query (wave 0, lane = query) ----
    if (t < 64) {
        float B0 = 3e38f, B1 = 3e38f, B2v = 3e38f;
        int   I0 = 0, I1 = 0, I2 = 0;
        #pragma unroll
        for (int ww = 0; ww < NW; ++ww) {          // ascending wave = ascending j
            const int ci = (ww * 64 + t) * 3;
            insert3(candD[ci+0], candI[ci+0], B0,B1,B2v, I0,I1,I2);
            insert3(candD[ci+1], candI[ci+1], B0,B1,B2v, I0,I1,I2);
            insert3(candD[ci+2], candI[ci+2], B0,B1,B2v, I0,I1,I2);
        }
        // exact d2 = surrogate d' + |q|^2 (verified rounds 2-5)
        const float qq = qx*qx + qy*qy + qz*qz;
        const float w0 = 1.0f / fmaxf(B0  + qq, 1e-16f);
        const float w1 = 1.0f / fmaxf(B1  + qq, 1e-16f);
        const float w2 = 1.0f / fmaxf(B2v + qq, 1e-16f);
        const float inv = 1.0f / (w0 + w1 + w2);
        idxL[t*3+0] = I0; idxL[t*3+1] = I1; idxL[t*3+2] = I2;
        wnL[t*3+0] = w0*inv; wnL[t*3+1] = w1*inv; wnL[t*3+2] = w2*inv;
    }
    __syncthreads();   // posL dead from here; candD/I dead after this barrier

    const int ln = lane & 15, kq = lane >> 4;
    const int wm  = (wave >> 2) * 16;   // 4 m-wave-rows of 16
    const int wnc = (wave & 3) * 64;    // 4 n-wave-cols of 64

    // ---- weight frag prefetch (k=0,32): in flight during gather ----
    bf16x8 bfA[4], bfB[4];
    #pragma unroll
    for (int nt = 0; nt < 4; ++nt) {
        bfA[nt] = *(const bf16x8*)(W1t + (size_t)(wnc + nt*16 + ln) * C_H +  0 + kq*8);
        bfB[nt] = *(const bf16x8*)(W1t + (size_t)(wnc + nt*16 + ln) * C_H + 32 + kq*8);
    }

    // ---- Phase C: skip concat (from regs) + gather-interp into h ----
    #pragma unroll
    for (int p = 0; p < 2; ++p) {
        const int g = p * 1024 + t;
        const int r = g >> 5, c = (g & 31) * 4;
        union { __hip_bfloat162 v2[2]; uint2 u; } pk;
        pk.v2[0].x = __float2bfloat16(skipv[p].x); pk.v2[0].y = __float2bfloat16(skipv[p].y);
        pk.v2[1].x = __float2bfloat16(skipv[p].z); pk.v2[1].y = __float2bfloat16(skipv[p].w);
        *(uint2*)&h[(size_t)r * 392 + C_IN + c] = pk.u;
    }
    #pragma unroll 4
    for (int p = 0; p < 4; ++p) {
        const int g = p * 1024 + t;                // 0..4095
        const int r = g >> 6, c = (g & 63) * 4;
        const int   i0 = idxL[r*3+0], i1 = idxL[r*3+1], i2 = idxL[r*3+2];
        const float w0 = wnL[r*3+0],  w1 = wnL[r*3+1],  w2 = wnL[r*3+2];
        const float4 v0 = *(const float4*)(x + (size_t)i0 * C_IN + c);
        const float4 v1 = *(const float4*)(x + (size_t)i1 * C_IN + c);
        const float4 v2 = *(const float4*)(x + (size_t)i2 * C_IN + c);
        union { __hip_bfloat162 v2_[2]; uint2 u; } pk;
        pk.v2_[0].x = __float2bfloat16(w0*v0.x + w1*v1.x + w2*v2.x);
        pk.v2_[0].y = __float2bfloat16(w0*v0.y + w1*v1.y + w2*v2.y);
        pk.v2_[1].x = __float2bfloat16(w0*v0.z + w1*v1.z + w2*v2.z);
        pk.v2_[1].y = __float2bfloat16(w0*v0.w + w1*v1.w + w2*v2.w);
        *(uint2*)&h[(size_t)r * 392 + c] = pk.u;
    }
    __syncthreads();   // h complete

    f32x4 acc[4] = {};

    // ---- stage 1: hid = relu(h @ W1t^T + b1), K=384, barrier-free ----
    // reg-double-buffered W1 frags; full unroll -> compile-time buffer parity
    #pragma unroll
    for (int s = 0; s < 12; ++s) {
        const int k0 = s * 32;
        bf16x8* bc = (s & 1) ? bfB : bfA;
        const bf16x8 a0 = *(const bf16x8*)&h[(size_t)(wm + ln) * 392 + k0 + kq*8];
        #pragma unroll
        for (int nt = 0; nt < 4; ++nt)
            acc[nt] = __builtin_amdgcn_mfma_f32_16x16x32_bf16(a0, bc[nt], acc[nt], 0,0,0);
        if (s < 10) {                              // refill for step s+2 (W1)
            #pragma unroll
            for (int nt = 0; nt < 4; ++nt)
                bc[nt] = *(const bf16x8*)(W1t + (size_t)(wnc + nt*16 + ln) * C_H + (k0 + 64) + kq*8);
        } else {                                   // first W2 tiles (stage-2 steps 0,1)
            #pragma unroll
            for (int nt = 0; nt < 4; ++nt)
                bc[nt] = *(const bf16x8*)(W2t + (size_t)(wnc + nt*16 + ln) * HDIM + (s - 10) * 32 + kq*8);
        }
    }

    // stage-1 epilogue: bias + relu -> hid (LDS), reset acc
    #pragma unroll
    for (int nt = 0; nt < 4; ++nt) {
        const int n = wnc + nt*16 + ln;
        const float bv = b1[n];
        const int rbase = wm + kq*4;
        #pragma unroll
        for (int r = 0; r < 4; ++r) {
            const float v = fmaxf(acc[nt][r] + bv, 0.0f);
            hid[(size_t)(rbase + r) * 264 + n] = __float2bfloat16(v);
            acc[nt][r] = 0.0f;
        }
    }
    __syncthreads();

    // ---- stage 2: out = hid @ W2t^T + b2, K=256, barrier-free ----
    #pragma unroll
    for (int s = 0; s < 8; ++s) {
        const int k0 = s * 32;
        bf16x8* bc = (s & 1) ? bfB : bfA;          // parity continues from stage 1
        const bf16x8 a0 = *(const bf16x8*)&hid[(size_t)(wm + ln) * 264 + k0 + kq*8];
        #pragma unroll
        for (int nt = 0; nt < 4; ++nt)
            acc[nt] = __builtin_amdgcn_mfma_f32_16x16x32_bf16(a0, bc[nt], acc[nt], 0,0,0);
        if (s < 6) {
            #pragma unroll
            for (int nt = 0; nt < 4; ++nt)
                bc[nt] = *(const bf16x8*)(W2t + (size_t)(wnc + nt*16 + ln) * HDIM + (k0 + 64) + kq*8);
        }
    }

    // stage-2 epilogue: bias -> out (fp32)
    #pragma unroll
    for (int nt = 0; nt < 4; ++nt) {
        const int n = wnc + nt*16 + ln;
        const float bv = b2[n];
        const int rbase = m0 + wm + kq*4;
        #pragma unroll
        for (int r = 0; r < 4; ++r)
            out[(size_t)(rbase + r) * HDIM + n] = acc[nt][r] + bv;
    }
}

extern "C" void kernel_launch(void* const* d_in, const int* in_sizes, int n_in,
                              void* d_out, int out_size, void* d_ws, size_t ws_size,
                              hipStream_t stream) {
    (void)in_sizes; (void)n_in; (void)ws_size;
    const float* x        = (const float*)d_in[0];   // [4096,256]
    const float* pos      = (const float*)d_in[1];   // [4096,3]
    const float* x_skip   = (const float*)d_in[3];   // [16384,128]
    const float* pos_skip = (const float*)d_in[4];   // [16384,3]
    const float* W1       = (const float*)d_in[6];   // [384,256]
    const float* b1       = (const float*)d_in[7];   // [256]
    const float* W2       = (const float*)d_in[8];   // [256,256]
    const float* b2       = (const float*)d_in[9];   // [256]
    float* out = (float*)d_out;

    char* ws = (char*)d_ws;
    __hip_bfloat16* W1t  = (__hip_bfloat16*)(ws);           // 196,608
    __hip_bfloat16* W2t  = (__hip_bfloat16*)(ws + 196608);  // 131,072
    float4*         pos4 = (float4*)(ws + 327680);          //  65,536
                                                            // total 384 KB

    prep_tail_kernel<<<(C_H*HDIM + HDIM*HDIM + N_PTS + 255)/256, 256, 0, stream>>>(
        W1, W2, pos, pos_skip, W1t, W2t, pos4, out, out_size);
    mega_kernel<<<M_Q/QB, 1024, 0, stream>>>(
        pos4, pos_skip, x, x_skip, (const __bf16*)W1t, (const __bf16*)W2t, b1, b2, out);
}

// Round 7
// 151.428 us; speedup vs baseline: 1.0539x; 1.0539x over previous
//
#include <hip/hip_runtime.h>
#include <hip/hip_bf16.h>

#define N_PTS  4096
#define M_Q    16384
#define C_IN   256
#define C_SKIP 128
#define C_H    384      // C_IN + C_SKIP
#define HDIM   256
#define QB     64       // queries per block -> 256 blocks = 1/CU

typedef __bf16 bf16x8 __attribute__((ext_vector_type(8)));
typedef float  f32x4  __attribute__((ext_vector_type(4)));

__device__ __forceinline__ void insert3(float d, int j,
                                        float& b0, float& b1, float& b2,
                                        int& i0, int& i1, int& i2) {
    if (d < b2) {
        if (d < b1) {
            b2 = b1; i2 = i1;
            if (d < b0) { b1 = b0; i1 = i0; b0 = d; i0 = j; }
            else        { b1 = d;  i1 = j; }
        } else { b2 = d; i2 = j; }
    }
}

// ---- Phase 0: fused prep — W1/W2 convert+transpose, pos4 build, out tail ---
__global__ __launch_bounds__(256) void prep_tail_kernel(
        const float* __restrict__ W1, const float* __restrict__ W2,
        const float* __restrict__ pos, const float* __restrict__ pos_skip,
        __hip_bfloat16* __restrict__ W1t, __hip_bfloat16* __restrict__ W2t,
        float4* __restrict__ pos4, float* __restrict__ out, int out_size) {
    const int i = blockIdx.x * 256 + threadIdx.x;
    if (i < C_H * HDIM) {
        const int k = i / HDIM, n = i % HDIM;
        W1t[n * C_H + k] = __float2bfloat16(W1[i]);
    } else if (i < C_H * HDIM + HDIM * HDIM) {
        const int j = i - C_H * HDIM;
        const int k = j / HDIM, n = j % HDIM;
        W2t[n * HDIM + k] = __float2bfloat16(W2[j]);
    } else if (i < C_H * HDIM + HDIM * HDIM + N_PTS) {
        const int j = i - (C_H * HDIM + HDIM * HDIM);
        const float px = pos[j*3+0], py = pos[j*3+1], pz = pos[j*3+2];
        pos4[j] = make_float4(px, py, pz, px*px + py*py + pz*pz);
    }
    // output tail: pos_skip passthrough + zero pad (runs before mega writes)
    if (i < M_Q * 3) out[(size_t)M_Q * HDIM + i] = pos_skip[i];
    const int zbase = M_Q * HDIM + M_Q * 3;
    if (zbase + i < out_size) out[zbase + i] = 0.0f;
}

// ---- Mega kernel v5: s_load point stream + single-arena LDS overlay --------
// 64 queries/block, 512 thr = 8 waves, grid 256 = 1 block/CU (r5 structure).
// Phase A: kNN scan reads pos4 DIRECTLY FROM GLOBAL with wave-uniform index
// (readfirstlane) -> s_load_dwordx4 SGPR broadcast: scalar-mem pipe, zero
// LDS-pipe occupancy (r5 burned the LDS crossbar on 4096 ds_read_b128
// broadcasts). Phase B: wave-0 merge. Phase C: gather+skip into h. GEMM1 ->
// (barrier) -> hid OVERLAYS h -> GEMM2 -> out. One 51.7 KB arena:
// cand(12K) / h(50.2K) / hid(33.8K) all phase-disjoint at offset 0.
__global__ __launch_bounds__(512) void mega_kernel(
        const float4* __restrict__ pos4, const float* __restrict__ pos_skip,
        const float* __restrict__ x, const float* __restrict__ x_skip,
        const __bf16* __restrict__ W1t, const __bf16* __restrict__ W2t,
        const float* __restrict__ b1, const float* __restrict__ b2,
        float* __restrict__ out) {
    __shared__ __align__(16) char smem[51712];
    __hip_bfloat16* h     = (__hip_bfloat16*)smem;            // [64][392] 50.2 KB (phase C..GEMM1)
    __hip_bfloat16* hid   = (__hip_bfloat16*)smem;            // [64][264] 33.8 KB (overlays h, post-GEMM1)
    float*          candD = (float*)smem;                     // [8][64][3] 6 KB (phase A/B)
    int*            candI = (int*)  (smem + 6144);            // [8][64][3] 6 KB
    int*            idxL  = (int*)  (smem + 50176);           // [192]
    float*          wnL   = (float*)(smem + 50944);           // [192]

    const int t    = threadIdx.x;
    const int m0   = blockIdx.x * QB;
    const int wave = t >> 6, lane = t & 63;

    // ---- preload x_skip to regs: consumed in phase C (issue-early) ----
    float4 skipv[4];
    #pragma unroll
    for (int p = 0; p < 4; ++p) {
        const int g = p * 512 + t;                 // 0..2047
        const int r = g >> 5, c = (g & 31) * 4;
        skipv[p] = *(const float4*)(x_skip + (size_t)(m0 + r) * C_SKIP + c);
    }

    const int q = m0 + lane;
    const float qx = pos_skip[q*3+0], qy = pos_skip[q*3+1], qz = pos_skip[q*3+2];
    const float m2x = -2.0f * qx, m2y = -2.0f * qy, m2z = -2.0f * qz;

    // ---- Phase A: kNN scan; wave w owns points [w*512,(w+1)*512) ----
    // wave-uniform index (readfirstlane) -> s_load_dwordx4 broadcast
    {
        const int j0 = __builtin_amdgcn_readfirstlane(wave * (N_PTS / 8));
        float bb0 = 3e38f, bb1 = 3e38f, bb2 = 3e38f;
        int   ii0 = 0, ii1 = 0, ii2 = 0;
        #pragma unroll 8
        for (int j = 0; j < N_PTS / 8; ++j) {
            const float4 p = pos4[j0 + j];         // uniform addr -> scalar load
            const float d = fmaf(p.x, m2x, fmaf(p.y, m2y, fmaf(p.z, m2z, p.w)));
            const int  jj = j0 + j;
            const bool c0 = d < bb0, c1 = d < bb1, c2 = d < bb2;
            ii2 = c2 ? (c1 ? ii1 : jj) : ii2;
            ii1 = c1 ? (c0 ? ii0 : jj) : ii1;
            ii0 = c0 ? jj : ii0;
            bb2 = __builtin_amdgcn_fmed3f(d, bb1, bb2);  // branch-free top-3 values
            bb1 = __builtin_amdgcn_fmed3f(d, bb0, bb1);
            bb0 = fminf(bb0, d);
        }
        const int ci = (wave * 64 + lane) * 3;
        candD[ci+0] = bb0; candD[ci+1] = bb1; candD[ci+2] = bb2;
        candI[ci+0] = ii0; candI[ci+1] = ii1; candI[ci+2] = ii2;
    }
    __syncthreads();

    // ---- Phase B: merge 24 cands/query (wave 0, lane = query) ----
    if (t < 64) {
        float B0 = 3e38f, B1 = 3e38f, B2v = 3e38f;
        int   I0 = 0, I1 = 0, I2 = 0;
        #pragma unroll
        for (int ww = 0; ww < 8; ++ww) {           // ascending wave = ascending j
            const int ci = (ww * 64 + t) * 3;
            insert3(candD[ci+0], candI[ci+0], B0,B1,B2v, I0,I1,I2);
            insert3(candD[ci+1], candI[ci+1], B0,B1,B2v, I0,I1,I2);
            insert3(candD[ci+2], candI[ci+2], B0,B1,B2v, I0,I1,I2);
        }
        // exact d2 = surrogate d' + |q|^2 (verified rounds 2-6)
        const float qq = qx*qx + qy*qy + qz*qz;
        const float w0 = 1.0f / fmaxf(B0  + qq, 1e-16f);
        const float w1 = 1.0f / fmaxf(B1  + qq, 1e-16f);
        const float w2 = 1.0f / fmaxf(B2v + qq, 1e-16f);
        const float inv = 1.0f / (w0 + w1 + w2);
        idxL[t*3+0] = I0; idxL[t*3+1] = I1; idxL[t*3+2] = I2;
        wnL[t*3+0] = w0*inv; wnL[t*3+1] = w1*inv; wnL[t*3+2] = w2*inv;
    }
    __syncthreads();   // cand dead from here; h arena free

    const int ln = lane & 15, kq = lane >> 4;
    const int wm  = (wave >> 2) * 32;   // 2 m-wave-rows of 32
    const int wnc = (wave & 3) * 64;    // 4 n-wave-cols of 64

    // ---- weight frag prefetch (k=0,32): in flight during gather ----
    bf16x8 bfA[4], bfB[4];
    #pragma unroll
    for (int nt = 0; nt < 4; ++nt) {
        bfA[nt] = *(const bf16x8*)(W1t + (size_t)(wnc + nt*16 + ln) * C_H +  0 + kq*8);
        bfB[nt] = *(const bf16x8*)(W1t + (size_t)(wnc + nt*16 + ln) * C_H + 32 + kq*8);
    }

    // ---- Phase C: skip concat (from regs) + gather-interp into h ----
    #pragma unroll
    for (int p = 0; p < 4; ++p) {
        const int g = p * 512 + t;
        const int r = g >> 5, c = (g & 31) * 4;
        union { __hip_bfloat162 v2[2]; uint2 u; } pk;
        pk.v2[0].x = __float2bfloat16(skipv[p].x); pk.v2[0].y = __float2bfloat16(skipv[p].y);
        pk.v2[1].x = __float2bfloat16(skipv[p].z); pk.v2[1].y = __float2bfloat16(skipv[p].w);
        *(uint2*)&h[(size_t)r * 392 + C_IN + c] = pk.u;
    }
    #pragma unroll 4
    for (int p = 0; p < 8; ++p) {
        const int g = p * 512 + t;                 // 0..4095
        const int r = g >> 6, c = (g & 63) * 4;
        const int   i0 = idxL[r*3+0], i1 = idxL[r*3+1], i2 = idxL[r*3+2];
        const float w0 = wnL[r*3+0],  w1 = wnL[r*3+1],  w2 = wnL[r*3+2];
        const float4 v0 = *(const float4*)(x + (size_t)i0 * C_IN + c);
        const float4 v1 = *(const float4*)(x + (size_t)i1 * C_IN + c);
        const float4 v2 = *(const float4*)(x + (size_t)i2 * C_IN + c);
        union { __hip_bfloat162 v2_[2]; uint2 u; } pk;
        pk.v2_[0].x = __float2bfloat16(w0*v0.x + w1*v1.x + w2*v2.x);
        pk.v2_[0].y = __float2bfloat16(w0*v0.y + w1*v1.y + w2*v2.y);
        pk.v2_[1].x = __float2bfloat16(w0*v0.z + w1*v1.z + w2*v2.z);
        pk.v2_[1].y = __float2bfloat16(w0*v0.w + w1*v1.w + w2*v2.w);
        *(uint2*)&h[(size_t)r * 392 + c] = pk.u;
    }
    __syncthreads();   // h complete

    f32x4 acc[2][4] = {};

    // ---- stage 1: hid = relu(h @ W1t^T + b1), K=384, barrier-free ----
    // reg-double-buffered W1 frags; full unroll -> compile-time buffer parity
    #pragma unroll
    for (int s = 0; s < 12; ++s) {
        const int k0 = s * 32;
        bf16x8* bc = (s & 1) ? bfB : bfA;
        const bf16x8 a0 = *(const bf16x8*)&h[(size_t)(wm +      ln) * 392 + k0 + kq*8];
        const bf16x8 a1 = *(const bf16x8*)&h[(size_t)(wm + 16 + ln) * 392 + k0 + kq*8];
        #pragma unroll
        for (int nt = 0; nt < 4; ++nt)
            acc[0][nt] = __builtin_amdgcn_mfma_f32_16x16x32_bf16(a0, bc[nt], acc[0][nt], 0,0,0);
        #pragma unroll
        for (int nt = 0; nt < 4; ++nt)
            acc[1][nt] = __builtin_amdgcn_mfma_f32_16x16x32_bf16(a1, bc[nt], acc[1][nt], 0,0,0);
        if (s < 10) {                              // refill for step s+2 (W1)
            #pragma unroll
            for (int nt = 0; nt < 4; ++nt)
                bc[nt] = *(const bf16x8*)(W1t + (size_t)(wnc + nt*16 + ln) * C_H + (k0 + 64) + kq*8);
        } else {                                   // first W2 tiles (stage-2 steps 0,1)
            #pragma unroll
            for (int nt = 0; nt < 4; ++nt)
                bc[nt] = *(const bf16x8*)(W2t + (size_t)(wnc + nt*16 + ln) * HDIM + (s - 10) * 32 + kq*8);
        }
    }
    __syncthreads();   // all h reads done -> arena reusable as hid

    // stage-1 epilogue: bias + relu -> hid (overlays h), reset acc
    #pragma unroll
    for (int nt = 0; nt < 4; ++nt) {
        const int n = wnc + nt*16 + ln;
        const float bv = b1[n];
        #pragma unroll
        for (int mt = 0; mt < 2; ++mt) {
            const int rbase = wm + mt*16 + kq*4;
            #pragma unroll
            for (int r = 0; r < 4; ++r) {
                const float v = fmaxf(acc[mt][nt][r] + bv, 0.0f);
                hid[(size_t)(rbase + r) * 264 + n] = __float2bfloat16(v);
                acc[mt][nt][r] = 0.0f;
            }
        }
    }
    __syncthreads();

    // ---- stage 2: out = hid @ W2t^T + b2, K=256, barrier-free ----
    #pragma unroll
    for (int s = 0; s < 8; ++s) {
        const int k0 = s * 32;
        bf16x8* bc = (s & 1) ? bfB : bfA;          // parity continues from stage 1
        const bf16x8 a0 = *(const bf16x8*)&hid[(size_t)(wm +      ln) * 264 + k0 + kq*8];
        const bf16x8 a1 = *(const bf16x8*)&hid[(size_t)(wm + 16 + ln) * 264 + k0 + kq*8];
        #pragma unroll
        for (int nt = 0; nt < 4; ++nt)
            acc[0][nt] = __builtin_amdgcn_mfma_f32_16x16x32_bf16(a0, bc[nt], acc[0][nt], 0,0,0);
        #pragma unroll
        for (int nt = 0; nt < 4; ++nt)
            acc[1][nt] = __builtin_amdgcn_mfma_f32_16x16x32_bf16(a1, bc[nt], acc[1][nt], 0,0,0);
        if (s < 6) {
            #pragma unroll
            for (int nt = 0; nt < 4; ++nt)
                bc[nt] = *(const bf16x8*)(W2t + (size_t)(wnc + nt*16 + ln) * HDIM + (k0 + 64) + kq*8);
        }
    }

    // stage-2 epilogue: bias -> out (fp32)
    #pragma unroll
    for (int nt = 0; nt < 4; ++nt) {
        const int n = wnc + nt*16 + ln;
        const float bv = b2[n];
        #pragma unroll
        for (int mt = 0; mt < 2; ++mt) {
            const int rbase = m0 + wm + mt*16 + kq*4;
            #pragma unroll
            for (int r = 0; r < 4; ++r)
                out[(size_t)(rbase + r) * HDIM + n] = acc[mt][nt][r] + bv;
        }
    }
}

extern "C" void kernel_launch(void* const* d_in, const int* in_sizes, int n_in,
                              void* d_out, int out_size, void* d_ws, size_t ws_size,
                              hipStream_t stream) {
    (void)in_sizes; (void)n_in; (void)ws_size;
    const float* x        = (const float*)d_in[0];   // [4096,256]
    const float* pos      = (const float*)d_in[1];   // [4096,3]
    const float* x_skip   = (const float*)d_in[3];   // [16384,128]
    const float* pos_skip = (const float*)d_in[4];   // [16384,3]
    const float* W1       = (const float*)d_in[6];   // [384,256]
    const float* b1       = (const float*)d_in[7];   // [256]
    const float* W2       = (const float*)d_in[8];   // [256,256]
    const float* b2       = (const float*)d_in[9];   // [256]
    float* out = (float*)d_out;

    char* ws = (char*)d_ws;
    __hip_bfloat16* W1t  = (__hip_bfloat16*)(ws);           // 196,608
    __hip_bfloat16* W2t  = (__hip_bfloat16*)(ws + 196608);  // 131,072
    float4*         pos4 = (float4*)(ws + 327680);          //  65,536
                                                            // total 384 KB

    prep_tail_kernel<<<(C_H*HDIM + HDIM*HDIM + N_PTS + 255)/256, 256, 0, stream>>>(
        W1, W2, pos, pos_skip, W1t, W2t, pos4, out, out_size);
    mega_kernel<<<M_Q/QB, 512, 0, stream>>>(
        pos4, pos_skip, x, x_skip, (const __bf16*)W1t, (const __bf16*)W2t, b1, b2, out);
}

// Round 8
// 139.214 us; speedup vs baseline: 1.1464x; 1.0877x over previous
//
#include <hip/hip_runtime.h>
#include <hip/hip_bf16.h>

#define N_PTS  4096
#define M_Q    16384
#define C_IN   256
#define C_SKIP 128
#define C_H    384      // C_IN + C_SKIP
#define HDIM   256
#define QB     64       // queries per block -> 256 blocks = 1/CU
#define CANDMAX 24
#define EPSW   4e-3f    // capture window >= 2x worst-case MFMA d' error (~4e-4)

typedef __bf16 bf16x8 __attribute__((ext_vector_type(8)));
typedef float  f32x4  __attribute__((ext_vector_type(4)));

// prep segment boundaries
#define PW1  (C_H*HDIM)                    //  98304
#define PW2  (PW1 + HDIM*HDIM)             // 163840
#define PPV  (PW2 + N_PTS)                 // 167936
#define PAQ  (PPV + M_Q)                   // 184320

__device__ __forceinline__ unsigned short bfbits(float v) {
    __hip_bfloat16 b = __float2bfloat16(v);
    return *(unsigned short*)&b;
}
__device__ __forceinline__ float bff(unsigned short u) {
    __hip_bfloat16 b = *(__hip_bfloat16*)&u;
    return __bfloat162float(b);
}
// 3-way bf16 split: v = h + m + l + O(2^-27 v)
__device__ __forceinline__ void split3(float v, unsigned short& h,
                                       unsigned short& m, unsigned short& l) {
    h = bfbits(v);       float r  = v - bff(h);
    m = bfbits(r);       float r2 = r - bff(m);
    l = bfbits(r2);
}

// ---- Phase 0: prep — weights transpose, A/B distance K-vectors, out tail ---
// A-vec (per query q): 21 slots pairing with B-vec (per point p) so that
// mfma(A,B) = |p|^2 - 2 q.p in ~f32 accuracy:
//   per dim d: A[6d+..]=[ah,ah,am,ah,al,am], B[6d+..]=[bh,bm,bh,bl,bh,bm]
//   (a=-2q_d 3-split, b=p_d 3-split; missing cross terms ~2^-27)
//   k=18..20: A=[1,1,1], B=[pw_h,pw_m,pw_l]  (pw=|p|^2). k=21..31 zero.
__global__ __launch_bounds__(256) void prep_tail_kernel(
        const float* __restrict__ W1, const float* __restrict__ W2,
        const float* __restrict__ pos, const float* __restrict__ pos_skip,
        __hip_bfloat16* __restrict__ W1t, __hip_bfloat16* __restrict__ W2t,
        __hip_bfloat16* __restrict__ Aq, __hip_bfloat16* __restrict__ Pv,
        float* __restrict__ out, int out_size) {
    const int i = blockIdx.x * 256 + threadIdx.x;
    if (i < PW1) {
        const int k = i / HDIM, n = i % HDIM;
        W1t[n * C_H + k] = __float2bfloat16(W1[i]);
    } else if (i < PW2) {
        const int j = i - PW1;
        const int k = j / HDIM, n = j % HDIM;
        W2t[n * HDIM + k] = __float2bfloat16(W2[j]);
    } else if (i < PPV) {
        const int j = i - PW2;                       // point j -> Pv row
        const float px = pos[j*3+0], py = pos[j*3+1], pz = pos[j*3+2];
        const float pw = px*px + py*py + pz*pz;
        union { unsigned short u[32]; uint4 q[4]; } S;
        #pragma unroll
        for (int k = 0; k < 32; ++k) S.u[k] = 0;
        const float pd[3] = {px, py, pz};
        #pragma unroll
        for (int d = 0; d < 3; ++d) {
            unsigned short bh, bm, bl; split3(pd[d], bh, bm, bl);
            S.u[6*d+0] = bh; S.u[6*d+1] = bm; S.u[6*d+2] = bh;
            S.u[6*d+3] = bl; S.u[6*d+4] = bh; S.u[6*d+5] = bm;
        }
        unsigned short wh, wm, wl; split3(pw, wh, wm, wl);
        S.u[18] = wh; S.u[19] = wm; S.u[20] = wl;
        uint4* dst = (uint4*)(Pv + (size_t)j * 32);
        dst[0] = S.q[0]; dst[1] = S.q[1]; dst[2] = S.q[2]; dst[3] = S.q[3];
    } else if (i < PAQ) {
        const int j = i - PPV;                       // query j -> Aq row
        const float ax = -2.0f * pos_skip[j*3+0];
        const float ay = -2.0f * pos_skip[j*3+1];
        const float az = -2.0f * pos_skip[j*3+2];
        union { unsigned short u[32]; uint4 q[4]; } S;
        #pragma unroll
        for (int k = 0; k < 32; ++k) S.u[k] = 0;
        const float ad[3] = {ax, ay, az};
        #pragma unroll
        for (int d = 0; d < 3; ++d) {
            unsigned short ah, am, al; split3(ad[d], ah, am, al);
            S.u[6*d+0] = ah; S.u[6*d+1] = ah; S.u[6*d+2] = am;
            S.u[6*d+3] = ah; S.u[6*d+4] = al; S.u[6*d+5] = am;
        }
        const unsigned short one = bfbits(1.0f);
        S.u[18] = one; S.u[19] = one; S.u[20] = one;
        uint4* dst = (uint4*)(Aq + (size_t)j * 32);
        dst[0] = S.q[0]; dst[1] = S.q[1]; dst[2] = S.q[2]; dst[3] = S.q[3];
    }
    // output tail: pos_skip passthrough + zero pad
    if (i < M_Q * 3) out[(size_t)M_Q * HDIM + i] = pos_skip[i];
    const int zbase = M_Q * HDIM + M_Q * 3;
    if (zbase + i < out_size) out[zbase + i] = 0.0f;
}

// ---- Mega kernel v6: MFMA-kNN (values->capture->exact) + gather + MLP ------
// 64 q/block, 512 thr = 8 waves, grid 256. Wave w owns points [w*512,(w+1)*512).
// P1: 128 MFMAs (4 q-tiles x 32 p-tiles, C=0) -> values-only top3 (med3/min),
//     butterfly + wave0 merge -> bb2G[q] (3rd-best approx value).
// P2: MFMA recompute; capture d' <= bb2G+EPSW into per-query LDS lists.
// P3: wave0 exact f32 select on candidates (reference d2 formula + lex
//     tie-break) -> idxL/wnL.  Then gather h -> GEMM1 -> hid -> GEMM2 (r5).
__global__ __launch_bounds__(512) void mega_kernel(
        const __bf16* __restrict__ Aq, const __bf16* __restrict__ Pv,
        const float* __restrict__ pos, const float* __restrict__ pos_skip,
        const float* __restrict__ x, const float* __restrict__ x_skip,
        const __bf16* __restrict__ W1t, const __bf16* __restrict__ W2t,
        const float* __restrict__ b1, const float* __restrict__ b2,
        float* __restrict__ out) {
    __shared__ __align__(16) char smem[51968];
    __hip_bfloat16* h     = (__hip_bfloat16*)smem;            // [64][392] 50.2K (gather..GEMM1)
    __hip_bfloat16* hid   = (__hip_bfloat16*)smem;            // [64][264] overlays h post-GEMM1
    float*          candD = (float*)smem;                     // [8][64][3] 6K   (P1/merge)
    int*            candI = (int*)  (smem + 6144);            // [64][24]  6K   (P2/P3)
    int*            candC = (int*)  (smem + 12288);           // [64]      256B
    float*          bb2G  = (float*)(smem + 50176);           // [64]
    int*            idxL  = (int*)  (smem + 50432);           // [192]
    float*          wnL   = (float*)(smem + 51200);           // [192]

    const int t    = threadIdx.x;
    const int m0   = blockIdx.x * QB;
    const int wave = t >> 6, lane = t & 63;
    const int ln = lane & 15, kq = lane >> 4;

    if (t < 64) candC[t] = 0;

    // x_skip preload (consumed in gather phase)
    float4 skipv[4];
    #pragma unroll
    for (int p = 0; p < 4; ++p) {
        const int g = p * 512 + t;
        const int r = g >> 5, c = (g & 31) * 4;
        skipv[p] = *(const float4*)(x_skip + (size_t)(m0 + r) * C_SKIP + c);
    }

    // resident A-frags: 4 q-tiles x 8 bf16
    bf16x8 afq[4];
    #pragma unroll
    for (int qt = 0; qt < 4; ++qt)
        afq[qt] = *(const bf16x8*)(Aq + (size_t)(m0 + qt*16 + ln) * 32 + kq*8);

    const f32x4 zacc = {0.0f, 0.0f, 0.0f, 0.0f};
    const int ptbase = wave * 32;                  // p-tile base (16 pts each)

    // ---- Phase 1: MFMA distances, values-only top3 ----
    float b0_[4][4], b1_[4][4], b2_[4][4];
    #pragma unroll
    for (int qt = 0; qt < 4; ++qt)
        #pragma unroll
        for (int r = 0; r < 4; ++r) { b0_[qt][r]=3e38f; b1_[qt][r]=3e38f; b2_[qt][r]=3e38f; }

    bf16x8 bcur = *(const bf16x8*)(Pv + (size_t)(ptbase*16 + ln) * 32 + kq*8);
    for (int pt = 0; pt < 32; ++pt) {
        bf16x8 bnext;
        if (pt < 31)
            bnext = *(const bf16x8*)(Pv + (size_t)((ptbase+pt+1)*16 + ln) * 32 + kq*8);
        #pragma unroll
        for (int qt = 0; qt < 4; ++qt) {
            const f32x4 d = __builtin_amdgcn_mfma_f32_16x16x32_bf16(afq[qt], bcur, zacc, 0,0,0);
            #pragma unroll
            for (int r = 0; r < 4; ++r) {
                b2_[qt][r] = __builtin_amdgcn_fmed3f(d[r], b1_[qt][r], b2_[qt][r]);
                b1_[qt][r] = __builtin_amdgcn_fmed3f(d[r], b0_[qt][r], b1_[qt][r]);
                b0_[qt][r] = fminf(b0_[qt][r], d[r]);
            }
        }
        bcur = bnext;
    }
    // butterfly merge across the 16 lanes (ln) sharing each row-group
    #pragma unroll
    for (int qt = 0; qt < 4; ++qt)
        #pragma unroll
        for (int r = 0; r < 4; ++r) {
            float v0 = b0_[qt][r], v1 = b1_[qt][r], v2 = b2_[qt][r];
            #pragma unroll
            for (int m = 1; m <= 8; m <<= 1) {
                const float o0 = __shfl_xor(v0, m), o1 = __shfl_xor(v1, m), o2 = __shfl_xor(v2, m);
                const float mx  = fmaxf(v0, o0);
                const float z0  = fminf(v0, o0);
                const float mn1 = fminf(v1, o1);
                const float mn2 = fminf(v2, o2);
                v0 = z0;
                v1 = fminf(mx, mn1);
                v2 = __builtin_amdgcn_fmed3f(mx, mn1, mn2);
            }
            b0_[qt][r] = v0; b1_[qt][r] = v1; b2_[qt][r] = v2;
        }
    if (ln == 0) {
        #pragma unroll
        for (int qt = 0; qt < 4; ++qt)
            #pragma unroll
            for (int r = 0; r < 4; ++r) {
                const int base = (wave*64 + qt*16 + kq*4 + r) * 3;
                candD[base+0] = b0_[qt][r];
                candD[base+1] = b1_[qt][r];
                candD[base+2] = b2_[qt][r];
            }
    }
    __syncthreads();

    // ---- wave0: merge 8 wave-triples -> bb2G (3rd-best value) ----
    if (t < 64) {
        float B0 = 3e38f, B1 = 3e38f, B2 = 3e38f;
        #pragma unroll
        for (int ww = 0; ww < 8; ++ww) {
            const int base = (ww*64 + t) * 3;
            #pragma unroll
            for (int k = 0; k < 3; ++k) {
                const float v = candD[base+k];
                B2 = __builtin_amdgcn_fmed3f(v, B1, B2);
                B1 = __builtin_amdgcn_fmed3f(v, B0, B1);
                B0 = fminf(B0, v);
            }
        }
        bb2G[t] = B2;
    }
    __syncthreads();

    // ---- Phase 2: recompute + capture candidates within window ----
    float thr[4][4];
    #pragma unroll
    for (int qt = 0; qt < 4; ++qt)
        #pragma unroll
        for (int r = 0; r < 4; ++r)
            thr[qt][r] = bb2G[qt*16 + kq*4 + r] + EPSW;

    bcur = *(const bf16x8*)(Pv + (size_t)(ptbase*16 + ln) * 32 + kq*8);
    for (int pt = 0; pt < 32; ++pt) {
        bf16x8 bnext;
        if (pt < 31)
            bnext = *(const bf16x8*)(Pv + (size_t)((ptbase+pt+1)*16 + ln) * 32 + kq*8);
        const int pidx = (ptbase + pt) * 16 + ln;
        #pragma unroll
        for (int qt = 0; qt < 4; ++qt) {
            const f32x4 d = __builtin_amdgcn_mfma_f32_16x16x32_bf16(afq[qt], bcur, zacc, 0,0,0);
            const bool h0 = d[0] <= thr[qt][0], h1 = d[1] <= thr[qt][1];
            const bool h2 = d[2] <= thr[qt][2], h3 = d[3] <= thr[qt][3];
            if (__builtin_expect(h0|h1|h2|h3, 0)) {
                #pragma unroll
                for (int r = 0; r < 4; ++r) {
                    if (d[r] <= thr[qt][r]) {
                        const int row = qt*16 + kq*4 + r;
                        const int n = atomicAdd(&candC[row], 1);
                        if (n < CANDMAX) candI[row*CANDMAX + n] = pidx;
                    }
                }
            }
        }
        bcur = bnext;
    }
    __syncthreads();

    // ---- Phase 3: exact f32 select on candidates (wave0, lane = query) ----
    if (t < 64) {
        const int q = m0 + t;
        const float qx = pos_skip[q*3+0], qy = pos_skip[q*3+1], qz = pos_skip[q*3+2];
        int cnt = candC[t]; if (cnt > CANDMAX) cnt = CANDMAX;
        float e0 = 3e38f, e1 = 3e38f, e2 = 3e38f;
        int   i0 = 0x7fffffff, i1 = 0x7fffffff, i2 = 0x7fffffff;
        for (int c = 0; c < cnt; ++c) {
            const int j = candI[t*CANDMAX + c];
            const float dx = qx - pos[j*3+0];
            const float dy = qy - pos[j*3+1];
            const float dz = qz - pos[j*3+2];
            const float d2 = dx*dx + dy*dy + dz*dz;    // exact reference d2k
            // lexicographic (d2, idx) insert -> reference tie-break (lowest idx)
            const bool c2 = (d2 < e2) || (d2 == e2 && j < i2);
            if (c2) {
                const bool c1 = (d2 < e1) || (d2 == e1 && j < i1);
                if (c1) {
                    e2 = e1; i2 = i1;
                    const bool c0 = (d2 < e0) || (d2 == e0 && j < i0);
                    if (c0) { e1 = e0; i1 = i0; e0 = d2; i0 = j; }
                    else    { e1 = d2; i1 = j; }
                } else { e2 = d2; i2 = j; }
            }
        }
        const float w0 = 1.0f / fmaxf(e0, 1e-16f);
        const float w1 = 1.0f / fmaxf(e1, 1e-16f);
        const float w2 = 1.0f / fmaxf(e2, 1e-16f);
        const float inv = 1.0f / (w0 + w1 + w2);
        idxL[t*3+0] = i0; idxL[t*3+1] = i1; idxL[t*3+2] = i2;
        wnL[t*3+0] = w0*inv; wnL[t*3+1] = w1*inv; wnL[t*3+2] = w2*inv;
    }
    __syncthreads();   // cand region dead; h arena free

    const int wm  = (wave >> 2) * 32;   // 2 m-wave-rows of 32
    const int wnc = (wave & 3) * 64;    // 4 n-wave-cols of 64

    // ---- weight frag prefetch (k=0,32): in flight during gather ----
    bf16x8 bfA[4], bfB[4];
    #pragma unroll
    for (int nt = 0; nt < 4; ++nt) {
        bfA[nt] = *(const bf16x8*)(W1t + (size_t)(wnc + nt*16 + ln) * C_H +  0 + kq*8);
        bfB[nt] = *(const bf16x8*)(W1t + (size_t)(wnc + nt*16 + ln) * C_H + 32 + kq*8);
    }

    // ---- gather-interp + skip concat into h ----
    #pragma unroll
    for (int p = 0; p < 4; ++p) {
        const int g = p * 512 + t;
        const int r = g >> 5, c = (g & 31) * 4;
        union { __hip_bfloat162 v2[2]; uint2 u; } pk;
        pk.v2[0].x = __float2bfloat16(skipv[p].x); pk.v2[0].y = __float2bfloat16(skipv[p].y);
        pk.v2[1].x = __float2bfloat16(skipv[p].z); pk.v2[1].y = __float2bfloat16(skipv[p].w);
        *(uint2*)&h[(size_t)r * 392 + C_IN + c] = pk.u;
    }
    #pragma unroll 4
    for (int p = 0; p < 8; ++p) {
        const int g = p * 512 + t;                 // 0..4095
        const int r = g >> 6, c = (g & 63) * 4;
        const int   i0 = idxL[r*3+0], i1 = idxL[r*3+1], i2 = idxL[r*3+2];
        const float w0 = wnL[r*3+0],  w1 = wnL[r*3+1],  w2 = wnL[r*3+2];
        const float4 v0 = *(const float4*)(x + (size_t)i0 * C_IN + c);
        const float4 v1 = *(const float4*)(x + (size_t)i1 * C_IN + c);
        const float4 v2 = *(const float4*)(x + (size_t)i2 * C_IN + c);
        union { __hip_bfloat162 v2_[2]; uint2 u; } pk;
        pk.v2_[0].x = __float2bfloat16(w0*v0.x + w1*v1.x + w2*v2.x);
        pk.v2_[0].y = __float2bfloat16(w0*v0.y + w1*v1.y + w2*v2.y);
        pk.v2_[1].x = __float2bfloat16(w0*v0.z + w1*v1.z + w2*v2.z);
        pk.v2_[1].y = __float2bfloat16(w0*v0.w + w1*v1.w + w2*v2.w);
        *(uint2*)&h[(size_t)r * 392 + c] = pk.u;
    }
    __syncthreads();   // h complete

    f32x4 acc[2][4] = {};

    // ---- stage 1: hid = relu(h @ W1t^T + b1), K=384, barrier-free ----
    #pragma unroll
    for (int s = 0; s < 12; ++s) {
        const int k0 = s * 32;
        bf16x8* bc = (s & 1) ? bfB : bfA;
        const bf16x8 a0 = *(const bf16x8*)&h[(size_t)(wm +      ln) * 392 + k0 + kq*8];
        const bf16x8 a1 = *(const bf16x8*)&h[(size_t)(wm + 16 + ln) * 392 + k0 + kq*8];
        #pragma unroll
        for (int nt = 0; nt < 4; ++nt)
            acc[0][nt] = __builtin_amdgcn_mfma_f32_16x16x32_bf16(a0, bc[nt], acc[0][nt], 0,0,0);
        #pragma unroll
        for (int nt = 0; nt < 4; ++nt)
            acc[1][nt] = __builtin_amdgcn_mfma_f32_16x16x32_bf16(a1, bc[nt], acc[1][nt], 0,0,0);
        if (s < 10) {
            #pragma unroll
            for (int nt = 0; nt < 4; ++nt)
                bc[nt] = *(const bf16x8*)(W1t + (size_t)(wnc + nt*16 + ln) * C_H + (k0 + 64) + kq*8);
        } else {
            #pragma unroll
            for (int nt = 0; nt < 4; ++nt)
                bc[nt] = *(const bf16x8*)(W2t + (size_t)(wnc + nt*16 + ln) * HDIM + (s - 10) * 32 + kq*8);
        }
    }
    __syncthreads();   // all h reads done -> arena reusable as hid

    // stage-1 epilogue: bias + relu -> hid (overlays h), reset acc
    #pragma unroll
    for (int nt = 0; nt < 4; ++nt) {
        const int n = wnc + nt*16 + ln;
        const float bv = b1[n];
        #pragma unroll
        for (int mt = 0; mt < 2; ++mt) {
            const int rbase = wm + mt*16 + kq*4;
            #pragma unroll
            for (int r = 0; r < 4; ++r) {
                const float v = fmaxf(acc[mt][nt][r] + bv, 0.0f);
                hid[(size_t)(rbase + r) * 264 + n] = __float2bfloat16(v);
                acc[mt][nt][r] = 0.0f;
            }
        }
    }
    __syncthreads();

    // ---- stage 2: out = hid @ W2t^T + b2, K=256, barrier-free ----
    #pragma unroll
    for (int s = 0; s < 8; ++s) {
        const int k0 = s * 32;
        bf16x8* bc = (s & 1) ? bfB : bfA;
        const bf16x8 a0 = *(const bf16x8*)&hid[(size_t)(wm +      ln) * 264 + k0 + kq*8];
        const bf16x8 a1 = *(const bf16x8*)&hid[(size_t)(wm + 16 + ln) * 264 + k0 + kq*8];
        #pragma unroll
        for (int nt = 0; nt < 4; ++nt)
            acc[0][nt] = __builtin_amdgcn_mfma_f32_16x16x32_bf16(a0, bc[nt], acc[0][nt], 0,0,0);
        #pragma unroll
        for (int nt = 0; nt < 4; ++nt)
            acc[1][nt] = __builtin_amdgcn_mfma_f32_16x16x32_bf16(a1, bc[nt], acc[1][nt], 0,0,0);
        if (s < 6) {
            #pragma unroll
            for (int nt = 0; nt < 4; ++nt)
                bc[nt] = *(const bf16x8*)(W2t + (size_t)(wnc + nt*16 + ln) * HDIM + (k0 + 64) + kq*8);
        }
    }

    // stage-2 epilogue: bias -> out (fp32)
    #pragma unroll
    for (int nt = 0; nt < 4; ++nt) {
        const int n = wnc + nt*16 + ln;
        const float bv = b2[n];
        #pragma unroll
        for (int mt = 0; mt < 2; ++mt) {
            const int rbase = m0 + wm + mt*16 + kq*4;
            #pragma unroll
            for (int r = 0; r < 4; ++r)
                out[(size_t)(rbase + r) * HDIM + n] = acc[mt][nt][r] + bv;
        }
    }
}

extern "C" void kernel_launch(void* const* d_in, const int* in_sizes, int n_in,
                              void* d_out, int out_size, void* d_ws, size_t ws_size,
                              hipStream_t stream) {
    (void)in_sizes; (void)n_in; (void)ws_size;
    const float* x        = (const float*)d_in[0];   // [4096,256]
    const float* pos      = (const float*)d_in[1];   // [4096,3]
    const float* x_skip   = (const float*)d_in[3];   // [16384,128]
    const float* pos_skip = (const float*)d_in[4];   // [16384,3]
    const float* W1       = (const float*)d_in[6];   // [384,256]
    const float* b1       = (const float*)d_in[7];   // [256]
    const float* W2       = (const float*)d_in[8];   // [256,256]
    const float* b2       = (const float*)d_in[9];   // [256]
    float* out = (float*)d_out;

    char* ws = (char*)d_ws;
    __hip_bfloat16* W1t = (__hip_bfloat16*)(ws);             //   196,608
    __hip_bfloat16* W2t = (__hip_bfloat16*)(ws + 196608);    //   131,072
    __hip_bfloat16* Aq  = (__hip_bfloat16*)(ws + 327680);    // 1,048,576 (16384 x 32 bf16)
    __hip_bfloat16* Pv  = (__hip_bfloat16*)(ws + 1376256);   //   262,144 ( 4096 x 32 bf16)
                                                             // total ~1.64 MB

    prep_tail_kernel<<<(PAQ + 255)/256, 256, 0, stream>>>(
        W1, W2, pos, pos_skip, W1t, W2t, Aq, Pv, out, out_size);
    mega_kernel<<<M_Q/QB, 512, 0, stream>>>(
        (const __bf16*)Aq, (const __bf16*)Pv, pos, pos_skip, x, x_skip,
        (const __bf16*)W1t, (const __bf16*)W2t, b1, b2, out);
}